// Round 4
// baseline (409.627 us; speedup 1.0000x reference)
//
#include <hip/hip_runtime.h>

typedef unsigned short u16;
typedef unsigned int   u32;
typedef __attribute__((ext_vector_type(8))) __bf16 bf16x8;
typedef __attribute__((ext_vector_type(4))) float  f32x4;

#define AS1 __attribute__((address_space(1)))
#define AS3 __attribute__((address_space(3)))

// B=4096, K=64, D=128, H=2048, V=10000, IN=8640
// Permuted inp layout per row (8640 elems):
//   [0,128) u | [128,8320) v[k][d] | [8320,8576) extras k*4 | [8576,8640) popularity
// W1 rows permuted identically in transpose_w1.

__device__ __forceinline__ u16 f2bf(float f) {
  u32 u = __builtin_bit_cast(u32, f);
  u += 0x7fffu + ((u >> 16) & 1u);   // RNE (no NaN inputs here)
  return (u16)(u >> 16);
}

__device__ __forceinline__ float wred(float v) {
#pragma unroll
  for (int off = 32; off > 0; off >>= 1) v += __shfl_xor(v, off, 64);
  return v;
}

__device__ __forceinline__ void stage16(const u16* g, u16* l) {
  __builtin_amdgcn_global_load_lds((const AS1 void*)g, (AS3 void*)l, 16, 0, 0);
}

__device__ __forceinline__ int imin(int a, int b) { return a < b ? a : b; }

#define VMWAIT(infl) do { \
  if ((infl) >= 3)      asm volatile("s_waitcnt vmcnt(9)" ::: "memory"); \
  else if ((infl) == 2) asm volatile("s_waitcnt vmcnt(6)" ::: "memory"); \
  else if ((infl) == 1) asm volatile("s_waitcnt vmcnt(3)" ::: "memory"); \
  else                  asm volatile("s_waitcnt vmcnt(0)" ::: "memory"); \
} while (0)

// ---------------- feature kernel ----------------
__global__ __launch_bounds__(256) void feature_kernel(
    const float* __restrict__ te, const int* __restrict__ nidx,
    const float* __restrict__ freq, const float* __restrict__ lut,
    u16* __restrict__ inp)
{
  const int b = blockIdx.x;
  const int t = threadIdx.x;
  const int l = t & 63, w = t >> 6;
  __shared__ float u_sh[128];
  __shared__ float squ_sh;

  if (t < 128) u_sh[t] = te[(size_t)b * 128 + t];
  __syncthreads();
  if (w == 0) {
    float p = u_sh[l] * u_sh[l] + u_sh[l + 64] * u_sh[l + 64];
    p = wred(p);
    if (l == 0) squ_sh = p;
  }
  const size_t rb = (size_t)b * 8640;
  if (t < 64) {
    float2 u2 = *(const float2*)&u_sh[t * 2];
    u32 pk = (u32)f2bf(u2.x) | ((u32)f2bf(u2.y) << 16);
    *(u32*)&inp[rb + t * 2] = pk;
  }
  __syncthreads();

  const float squ = squ_sh;
  const float2 u2 = *(const float2*)&u_sh[l * 2];
  for (int k = w; k < 64; k += 4) {
    const int idx = nidx[b * 64 + k];
    const float2 v2 = *(const float2*)&lut[(size_t)idx * 128 + l * 2];
    float sqv = v2.x * v2.x + v2.y * v2.y;
    float dot = u2.x * v2.x + u2.y * v2.y;
    float dx = u2.x - v2.x, dy = u2.y - v2.y;
    float sqd = dx * dx + dy * dy;
    float sx = u2.x + v2.x, sy = u2.y + v2.y;
    float ssm = sx * sx + sy * sy;
    sqv = wred(sqv); dot = wred(dot); sqd = wred(sqd); ssm = wred(ssm);

    u32 pk = (u32)f2bf(v2.x) | ((u32)f2bf(v2.y) << 16);
    *(u32*)&inp[rb + 128 + (size_t)k * 128 + l * 2] = pk;

    if (l == 0) {
      float x = 1.0f + 2.0f * sqd / ((1.0f - squ) * (1.0f - sqv));
      x = fmaxf(x, 1.0f + 1e-5f);
      float poin = logf(x + sqrtf(x * x - 1.0f));
      float cosv = dot / fmaxf(sqrtf(squ) * sqrtf(sqv), 1e-8f);
      float pol  = (ssm - sqd) * 0.25f;
      u32 p0 = (u32)f2bf(poin) | ((u32)f2bf(cosv) << 16);
      u32 p1 = (u32)f2bf(pol)  | ((u32)f2bf(dot)  << 16);
      *(u32*)&inp[rb + 8320 + k * 4]     = p0;
      *(u32*)&inp[rb + 8320 + k * 4 + 2] = p1;
      inp[rb + 8576 + k] = f2bf(log1pf(freq[idx]));
    }
  }
}

// -------- W1 transpose with feature permutation: (8640,2048) f32 -> (2048,8640) bf16 --------
__device__ __forceinline__ int w1_orig_row(int p) {
  if (p < 128) return p;
  if (p < 8320) { int q = p - 128;  return 128 + (q >> 7) * 133 + (q & 127); }
  if (p < 8576) { int q = p - 8320; return 128 + (q >> 2) * 133 + 128 + (q & 3); }
  return 128 + (p - 8576) * 133 + 132;
}

__global__ __launch_bounds__(256) void transpose_w1(
    const float* __restrict__ in, u16* __restrict__ out)
{
  __shared__ u16 ls[64][65];
  const int p0 = (blockIdx.x >> 5) << 6;   // 135 p-tiles
  const int h0 = (blockIdx.x & 31) << 6;   // 32 h-tiles
  const int t = threadIdx.x;
  const int hl = t & 63, q = t >> 6;
#pragma unroll
  for (int i = 0; i < 16; i++) {
    int pl = i * 4 + q;
    int orig = w1_orig_row(p0 + pl);
    ls[pl][hl] = f2bf(in[(size_t)orig * 2048 + h0 + hl]);
  }
  __syncthreads();
  const int pr = t & 63;
#pragma unroll
  for (int i = 0; i < 16; i++) {
    int hc = i * 4 + q;
    out[(size_t)(h0 + hc) * 8640 + p0 + pr] = ls[pr][hc];
  }
}

// -------- generic transpose+convert: in (R,C) f32 -> out (C,R) bf16 --------
__global__ __launch_bounds__(256) void transpose_conv(
    const float* __restrict__ in, u16* __restrict__ out, int R, int C)
{
  __shared__ u16 ls[64][65];
  const int tiles_c = C >> 6;
  const int r0 = (blockIdx.x / tiles_c) << 6;
  const int c0 = (blockIdx.x % tiles_c) << 6;
  const int t = threadIdx.x;
  const int cl = t & 63, q = t >> 6;
#pragma unroll
  for (int i = 0; i < 16; i++) {
    int rl = i * 4 + q;
    ls[rl][cl] = f2bf(in[(size_t)(r0 + rl) * C + c0 + cl]);
  }
  __syncthreads();
  const int rr = t & 63;
#pragma unroll
  for (int i = 0; i < 16; i++) {
    int cc = i * 4 + q;
    out[(size_t)(c0 + cc) * R + r0 + rr] = ls[rr][cc];
  }
}

// ======== gemm8p: C(M,N) = relu(A(M,Kd)*BT(N,Kd)^T + bias), out bf16 ========
// BM=256, BN=128, BK=32. 512 thr = 8 waves as 4M x 2N, per-wave 64x64
// (acc[4][4]). HOMOGENEOUS waves: every wave MFMAs every K-tile so each SIMD
// has 2 concurrent MFMA streams (single wave can't saturate the pipe —
// round-3 lesson). Fragments double-buffered in NAMED regs (rule #20) via
// 2-unrolled K-loop: read tile tk+1 -> other buf, lgkmcnt(8) (old tile's
// reads done), sched_barrier(0) (rule #18), 16 MFMA, counted VMWAIT (T4,
// never 0 mid-loop), s_barrier. Ring of 6 LDS tile buffers (144KB), PF=5.
// T2 slot-XOR swizzle both-sides (rule #21): pre-swizzled GLOBAL source +
// linear global_load_lds dest + swizzled ds_read (verified: conflicts=0).
__global__ __launch_bounds__(512, 2) void gemm8p(
    const u16* __restrict__ A, const u16* __restrict__ BT,
    const float* __restrict__ bias, u16* __restrict__ out,
    int N, int Kd)
{
  extern __shared__ u16 lds[];   // 6 * 12288 u16 = 144KB
  const int t = threadIdx.x, l = t & 63, w = t >> 6;
  const int nb = N >> 7;
  const int cpx = gridDim.x >> 3;
  const int bid = (blockIdx.x & 7) * cpx + (blockIdx.x >> 3);
  const int bm = bid / nb, bn = bid % nb;
  const int m0 = bm << 8, n0 = bn << 7;

  const int vm = w >> 1, vn = w & 1;   // 4M x 2N wave grid

  const size_t lda = (size_t)Kd;
  const int NT = Kd >> 5;              // K-tiles of 32 (even for all our Kd)

  // ---- staging constants (pre-swizzled global source) ----
  const int qs  = (l & 7) ^ (l >> 3);           // logical slot this lane fetches
  const int rgo = 2 * (w * 8 + (l >> 3)) + (qs >> 2);
  const int cgo = (qs & 3) * 8;
  const u16* pA = A  + (size_t)(m0 + rgo) * lda + cgo;
  const u16* pB = BT + (size_t)(n0 + rgo) * lda + cgo;

  // ---- reader constants (swizzled ds_read addresses) ----
  const int lhalf = (l & 15) >> 1;
  const int qlog  = (l & 1) * 4 + (l >> 4);
  const int offc  = lhalf * 64 + (qlog ^ lhalf) * 8;
  const int aBase = vm * 2048 + offc;           // 64 rows = 32 lines per vm
  const int bBase = 8192 + vn * 2048 + offc;    // B region at 16KB

  f32x4 acc[4][4] = {};
  bf16x8 aA[4], bA[4], aB[4], bB[4];            // named frag double-buffers

  auto stage = [&](int tt) {
    const int s = (tt % 6) * 12288;
    const size_t kt = (size_t)tt * 32;
    stage16(pA + kt,             lds + s + w * 512);
    stage16(pA + 128 * lda + kt, lds + s + 4096 + w * 512);
    stage16(pB + kt,             lds + s + 8192 + w * 512);
  };
  auto rdA = [&](bf16x8* d, int tt) {
    const int s = (tt % 6) * 12288;
#pragma unroll
    for (int mi = 0; mi < 4; mi++) d[mi] = *(const bf16x8*)&lds[s + aBase + mi * 512];
  };
  auto rdB = [&](bf16x8* d, int tt) {
    const int s = (tt % 6) * 12288;
#pragma unroll
    for (int ni = 0; ni < 4; ni++) d[ni] = *(const bf16x8*)&lds[s + bBase + ni * 512];
  };
  auto mm = [&](const bf16x8* a, const bf16x8* b) {
    __builtin_amdgcn_s_setprio(1);
#pragma unroll
    for (int mi = 0; mi < 4; mi++)
#pragma unroll
      for (int ni = 0; ni < 4; ni++)
        acc[mi][ni] = __builtin_amdgcn_mfma_f32_16x16x32_bf16(a[mi], b[ni], acc[mi][ni], 0, 0, 0);
    __builtin_amdgcn_s_setprio(0);
  };

  // prologue: stage tiles 0..4; tiles 0,1 landed; read tile 0 -> buf A
  const int p_end = imin(NT - 1, 4);
  for (int tt = 0; tt <= p_end; ++tt) stage(tt);
  VMWAIT(p_end - imin(NT - 1, 1));
  __builtin_amdgcn_s_barrier();
  rdA(aA, 0); rdB(bA, 0);

  for (int tk = 0; tk < NT; tk += 2) {
    // -- sub-iter 0: compute tile tk (buf A), read tile tk+1 -> buf B
    if (tk + 5 < NT) stage(tk + 5);
    if (tk + 1 < NT) {
      rdA(aB, tk + 1); rdB(bB, tk + 1);
      asm volatile("s_waitcnt lgkmcnt(8)" ::: "memory");
    } else {
      asm volatile("s_waitcnt lgkmcnt(0)" ::: "memory");
    }
    __builtin_amdgcn_sched_barrier(0);
    mm(aA, bA);
    { const int hi = imin(tk + 5, NT - 1), lo = imin(tk + 2, NT - 1); VMWAIT(hi - lo); }
    __builtin_amdgcn_s_barrier();

    // -- sub-iter 1: compute tile tk+1 (buf B), read tile tk+2 -> buf A
    if (tk + 1 < NT) {
      if (tk + 6 < NT) stage(tk + 6);
      if (tk + 2 < NT) {
        rdA(aA, tk + 2); rdB(bA, tk + 2);
        asm volatile("s_waitcnt lgkmcnt(8)" ::: "memory");
      } else {
        asm volatile("s_waitcnt lgkmcnt(0)" ::: "memory");
      }
      __builtin_amdgcn_sched_barrier(0);
      mm(aB, bB);
      { const int hi = imin(tk + 6, NT - 1), lo = imin(tk + 3, NT - 1); VMWAIT(hi - lo); }
      __builtin_amdgcn_s_barrier();
    }
  }

  // ---- epilogue: direct write (no cross-group combine needed) ----
  const int rq = l >> 4, rl2 = l & 15;
#pragma unroll
  for (int mi = 0; mi < 4; mi++) {
#pragma unroll
    for (int ni = 0; ni < 4; ni++) {
      const int col = n0 + vn * 64 + ni * 16 + rl2;
      const float bv = bias[col];
#pragma unroll
      for (int j = 0; j < 4; j++) {
        const int row = m0 + vm * 64 + mi * 16 + rq * 4 + j;
        float vv = acc[mi][ni][j] + bv;
        out[(size_t)row * N + col] = f2bf(fmaxf(vv, 0.0f));
      }
    }
  }
}

// -------- final GEMM (N=64) fused: sigmoid -> dist, BCE partial per block --------
__global__ __launch_bounds__(256, 2) void gemm4_fused(
    const u16* __restrict__ A, const u16* __restrict__ BT,
    const float* __restrict__ bias, const float* __restrict__ oneh,
    float* __restrict__ dist, float* __restrict__ partial)
{
  __shared__ u16 lsA[2 * 128 * 32];
  __shared__ u16 lsB[2 * 64 * 32];
  __shared__ float red[256];
  const int t = threadIdx.x, l = t & 63, w = t >> 6;
  const int m0 = blockIdx.x << 7;
  const int wm = w >> 1, wn = w & 1;

  f32x4 acc[4][2] = {};
  const int srow = l >> 2, scol = (l & 3) * 8;

  const u16* pA0 = A  + (size_t)(m0 + w * 16 + srow)      * 2048 + scol;
  const u16* pA1 = A  + (size_t)(m0 + 64 + w * 16 + srow) * 2048 + scol;
  const u16* pB0 = BT + (size_t)(w * 16 + srow)           * 2048 + scol;

  auto stage = [&](int buf, int kt) {
    u16* dA = lsA + buf * 4096;
    u16* dB = lsB + buf * 2048;
    stage16(pA0 + kt, dA + w * 512);
    stage16(pA1 + kt, dA + 2048 + w * 512);
    stage16(pB0 + kt, dB + w * 512);
  };

  stage(0, 0);
  __syncthreads();

  const int kk = (l >> 4) * 8;
  const int rl = l & 15;
  int cur = 0;
  for (int kt = 0; kt < 2048; kt += 32) {
    if (kt + 32 < 2048) stage(cur ^ 1, kt + 32);
    const u16* sA = lsA + cur * 4096;
    const u16* sB = lsB + cur * 2048;
    bf16x8 a[4], bb[2];
#pragma unroll
    for (int mi = 0; mi < 4; mi++)
      a[mi] = *(const bf16x8*)&sA[(wm * 64 + mi * 16 + rl) * 32 + kk];
#pragma unroll
    for (int ni = 0; ni < 2; ni++)
      bb[ni] = *(const bf16x8*)&sB[(wn * 32 + ni * 16 + rl) * 32 + kk];
#pragma unroll
    for (int mi = 0; mi < 4; mi++)
#pragma unroll
      for (int ni = 0; ni < 2; ni++)
        acc[mi][ni] = __builtin_amdgcn_mfma_f32_16x16x32_bf16(a[mi], bb[ni], acc[mi][ni], 0, 0, 0);
    __syncthreads();
    cur ^= 1;
  }

  float lsum = 0.0f;
  const int rq = l >> 4, rl2 = l & 15;
#pragma unroll
  for (int mi = 0; mi < 4; mi++) {
#pragma unroll
    for (int ni = 0; ni < 2; ni++) {
      const int col = wn * 32 + ni * 16 + rl2;
      const float bv = bias[col];
#pragma unroll
      for (int j = 0; j < 4; j++) {
        const int row = m0 + wm * 64 + mi * 16 + rq * 4 + j;
        const float x = acc[mi][ni][j] + bv;
        const size_t o = (size_t)row * 64 + col;
        dist[o] = 1.0f / (1.0f + expf(-x));
        const float tt = oneh[o];
        lsum += fmaxf(x, 0.0f) - x * tt + log1pf(expf(-fabsf(x)));
      }
    }
  }
  red[t] = lsum;
  __syncthreads();
  for (int s = 128; s > 0; s >>= 1) {
    if (t < s) red[t] += red[t + s];
    __syncthreads();
  }
  if (t == 0) partial[blockIdx.x] = red[0];
}

__global__ void loss_final(const float* __restrict__ partial, float* __restrict__ outloss) {
  float v = (threadIdx.x < 32) ? partial[threadIdx.x] : 0.0f;
  v = wred(v);
  if (threadIdx.x == 0) outloss[0] = v * (1.0f / 262144.0f);
}

// ---------------- launch ----------------
extern "C" void kernel_launch(void* const* d_in, const int* in_sizes, int n_in,
                              void* d_out, int out_size, void* d_ws, size_t ws_size,
                              hipStream_t stream)
{
  const float* te   = (const float*)d_in[0];
  const int*   nidx = (const int*)  d_in[1];
  const float* oneh = (const float*)d_in[2];
  const float* freq = (const float*)d_in[3];
  const float* lut  = (const float*)d_in[4];
  const float* W1   = (const float*)d_in[5];
  const float* b1   = (const float*)d_in[6];
  const float* Wh1  = (const float*)d_in[7];
  const float* bh1  = (const float*)d_in[8];
  const float* Wh2  = (const float*)d_in[9];
  const float* bh2  = (const float*)d_in[10];
  const float* W2   = (const float*)d_in[11];
  const float* b2   = (const float*)d_in[12];

  float* dist  = (float*)d_out;          // 4096*64
  float* lossp = dist + 262144;          // +1

  size_t off = 0;
  char* base = (char*)d_ws;
  auto alloc = [&](size_t bytes) { char* p = base + off; off += (bytes + 255) & ~(size_t)255; return p; };
  u16* inp   = (u16*)alloc((size_t)4096 * 8640 * 2);
  u16* w1t   = (u16*)alloc((size_t)2048 * 8640 * 2);
  u16* wh1t  = (u16*)alloc((size_t)2048 * 2048 * 2);
  u16* wh2t  = (u16*)alloc((size_t)2048 * 2048 * 2);
  u16* w2t   = (u16*)alloc((size_t)64 * 2048 * 2);
  u16* h1    = (u16*)alloc((size_t)4096 * 2048 * 2);
  float* partial = (float*)alloc(1024);
  u16* h2 = inp;    // inp dead after GEMM1
  u16* h3 = w1t;    // w1t dead after GEMM1
  if (off > ws_size) return;  // workspace too small -> clean fail

  (void)hipFuncSetAttribute((const void*)gemm8p,
                            hipFuncAttributeMaxDynamicSharedMemorySize, 147456);

  feature_kernel<<<4096, 256, 0, stream>>>(te, nidx, freq, lut, inp);
  transpose_w1 <<<135 * 32, 256, 0, stream>>>(W1, w1t);
  transpose_conv<<<32 * 32, 256, 0, stream>>>(Wh1, wh1t, 2048, 2048);
  transpose_conv<<<32 * 32, 256, 0, stream>>>(Wh2, wh2t, 2048, 2048);
  transpose_conv<<<32 * 1, 256, 0, stream>>>(W2, w2t, 2048, 64);

  gemm8p<<<256, 512, 147456, stream>>>(inp, w1t, b1, h1, 2048, 8640);
  gemm8p<<<256, 512, 147456, stream>>>(h1, wh1t, bh1, h2, 2048, 2048);
  gemm8p<<<256, 512, 147456, stream>>>(h2, wh2t, bh2, h3, 2048, 2048);
  gemm4_fused  <<<32, 256, 0, stream>>>(h3, w2t, b2, oneh, dist, partial);
  loss_final   <<<1, 64, 0, stream>>>(partial, lossp);
}

// Round 5
// 379.239 us; speedup vs baseline: 1.0801x; 1.0801x over previous
//
#include <hip/hip_runtime.h>

typedef unsigned short u16;
typedef unsigned int   u32;
typedef __attribute__((ext_vector_type(8))) __bf16 bf16x8;
typedef __attribute__((ext_vector_type(4))) float  f32x4;

#define AS1 __attribute__((address_space(1)))
#define AS3 __attribute__((address_space(3)))

// B=4096, K=64, D=128, H=2048, V=10000, IN=8640
// Permuted inp layout per row (8640 elems):
//   [0,128) u | [128,8320) v[k][d] | [8320,8576) extras k*4 | [8576,8640) popularity
// W1 rows permuted identically in transpose_w1.

__device__ __forceinline__ u16 f2bf(float f) {
  u32 u = __builtin_bit_cast(u32, f);
  u += 0x7fffu + ((u >> 16) & 1u);   // RNE (no NaN inputs here)
  return (u16)(u >> 16);
}

__device__ __forceinline__ float wred(float v) {
#pragma unroll
  for (int off = 32; off > 0; off >>= 1) v += __shfl_xor(v, off, 64);
  return v;
}

__device__ __forceinline__ void stage16(const u16* g, u16* l) {
  __builtin_amdgcn_global_load_lds((const AS1 void*)g, (AS3 void*)l, 16, 0, 0);
}

// ---------------- feature kernel ----------------
__global__ __launch_bounds__(256) void feature_kernel(
    const float* __restrict__ te, const int* __restrict__ nidx,
    const float* __restrict__ freq, const float* __restrict__ lut,
    u16* __restrict__ inp)
{
  const int b = blockIdx.x;
  const int t = threadIdx.x;
  const int l = t & 63, w = t >> 6;
  __shared__ float u_sh[128];
  __shared__ float squ_sh;

  if (t < 128) u_sh[t] = te[(size_t)b * 128 + t];
  __syncthreads();
  if (w == 0) {
    float p = u_sh[l] * u_sh[l] + u_sh[l + 64] * u_sh[l + 64];
    p = wred(p);
    if (l == 0) squ_sh = p;
  }
  const size_t rb = (size_t)b * 8640;
  if (t < 64) {
    float2 u2 = *(const float2*)&u_sh[t * 2];
    u32 pk = (u32)f2bf(u2.x) | ((u32)f2bf(u2.y) << 16);
    *(u32*)&inp[rb + t * 2] = pk;
  }
  __syncthreads();

  const float squ = squ_sh;
  const float2 u2 = *(const float2*)&u_sh[l * 2];
  for (int k = w; k < 64; k += 4) {
    const int idx = nidx[b * 64 + k];
    const float2 v2 = *(const float2*)&lut[(size_t)idx * 128 + l * 2];
    float sqv = v2.x * v2.x + v2.y * v2.y;
    float dot = u2.x * v2.x + u2.y * v2.y;
    float dx = u2.x - v2.x, dy = u2.y - v2.y;
    float sqd = dx * dx + dy * dy;
    float sx = u2.x + v2.x, sy = u2.y + v2.y;
    float ssm = sx * sx + sy * sy;
    sqv = wred(sqv); dot = wred(dot); sqd = wred(sqd); ssm = wred(ssm);

    u32 pk = (u32)f2bf(v2.x) | ((u32)f2bf(v2.y) << 16);
    *(u32*)&inp[rb + 128 + (size_t)k * 128 + l * 2] = pk;

    if (l == 0) {
      float x = 1.0f + 2.0f * sqd / ((1.0f - squ) * (1.0f - sqv));
      x = fmaxf(x, 1.0f + 1e-5f);
      float poin = logf(x + sqrtf(x * x - 1.0f));
      float cosv = dot / fmaxf(sqrtf(squ) * sqrtf(sqv), 1e-8f);
      float pol  = (ssm - sqd) * 0.25f;
      u32 p0 = (u32)f2bf(poin) | ((u32)f2bf(cosv) << 16);
      u32 p1 = (u32)f2bf(pol)  | ((u32)f2bf(dot)  << 16);
      *(u32*)&inp[rb + 8320 + k * 4]     = p0;
      *(u32*)&inp[rb + 8320 + k * 4 + 2] = p1;
      inp[rb + 8576 + k] = f2bf(log1pf(freq[idx]));
    }
  }
}

// -------- W1 transpose with feature permutation: (8640,2048) f32 -> (2048,8640) bf16 --------
__device__ __forceinline__ int w1_orig_row(int p) {
  if (p < 128) return p;
  if (p < 8320) { int q = p - 128;  return 128 + (q >> 7) * 133 + (q & 127); }
  if (p < 8576) { int q = p - 8320; return 128 + (q >> 2) * 133 + 128 + (q & 3); }
  return 128 + (p - 8576) * 133 + 132;
}

__global__ __launch_bounds__(256) void transpose_w1(
    const float* __restrict__ in, u16* __restrict__ out)
{
  __shared__ u16 ls[64][65];
  const int p0 = (blockIdx.x >> 5) << 6;   // 135 p-tiles
  const int h0 = (blockIdx.x & 31) << 6;   // 32 h-tiles
  const int t = threadIdx.x;
  const int hl = t & 63, q = t >> 6;
#pragma unroll
  for (int i = 0; i < 16; i++) {
    int pl = i * 4 + q;
    int orig = w1_orig_row(p0 + pl);
    ls[pl][hl] = f2bf(in[(size_t)orig * 2048 + h0 + hl]);
  }
  __syncthreads();
  const int pr = t & 63;
#pragma unroll
  for (int i = 0; i < 16; i++) {
    int hc = i * 4 + q;
    out[(size_t)(h0 + hc) * 8640 + p0 + pr] = ls[pr][hc];
  }
}

// -------- generic transpose+convert: in (R,C) f32 -> out (C,R) bf16 --------
__global__ __launch_bounds__(256) void transpose_conv(
    const float* __restrict__ in, u16* __restrict__ out, int R, int C)
{
  __shared__ u16 ls[64][65];
  const int tiles_c = C >> 6;
  const int r0 = (blockIdx.x / tiles_c) << 6;
  const int c0 = (blockIdx.x % tiles_c) << 6;
  const int t = threadIdx.x;
  const int cl = t & 63, q = t >> 6;
#pragma unroll
  for (int i = 0; i < 16; i++) {
    int rl = i * 4 + q;
    ls[rl][cl] = f2bf(in[(size_t)(r0 + rl) * C + c0 + cl]);
  }
  __syncthreads();
  const int rr = t & 63;
#pragma unroll
  for (int i = 0; i < 16; i++) {
    int cc = i * 4 + q;
    out[(size_t)(c0 + cc) * R + r0 + rr] = ls[rr][cc];
  }
}

// ======== gemm8p: C(M,N) = relu(A(M,Kd)*BT(N,Kd)^T + bias), out bf16 ========
// BM=256 BN=128 BK=64. 512 thr = 8 waves = 2 K-subgroups (kg=w>>2) x (2Mx2N).
// Every wave owns a 128x64 output tile (acc[8][4], 42.7 FLOP/LDS-byte) and
// MFMAs EVERY interval on its K32 half -> 2 MFMA streams/SIMD (R4 lesson)
// AND minimal LDS reads (R3 lesson). m201 rhythm: 2 phases/interval, each
// {ds_read frags + 3 global_load_lds -> bar -> lgkm(0)+sched_barrier ->
// setprio+16 MFMA -> bar}; ONE counted vmcnt(6) per interval (T4; never 0
// mid-loop). Ring-3 x 48KB LDS, prefetch depth 2. T2 slot-XOR swizzle
// (row-line layout: line=128B=one 64-col row, phys_slot = chunk ^ (row&7)),
// pre-swizzled global source + linear gload_lds dest + swizzled ds_read
// (rule #21; element-traced). K-group partials combined via LDS (R3 path).
__global__ __launch_bounds__(512, 2) void gemm8p(
    const u16* __restrict__ A, const u16* __restrict__ BT,
    const float* __restrict__ bias, u16* __restrict__ out,
    int N, int Kd)
{
  extern __shared__ u16 lds[];   // 3 * 24576 u16 = 144KB
  const int t = threadIdx.x, l = t & 63, w = t >> 6;
  const int nb = N >> 7;
  const int cpx = gridDim.x >> 3;
  const int bid = (blockIdx.x & 7) * cpx + (blockIdx.x >> 3);
  const int bm = bid / nb, bn = bid % nb;
  const int m0 = bm << 8, n0 = bn << 7;

  const int kg = w >> 2;               // K32-subgroup within BK=64
  const int p  = w & 3;                // wave position
  const int vm = p >> 1, vn = p & 1;   // 2M x 2N

  const size_t lda = (size_t)Kd;
  const int NT = Kd >> 6;              // K-tiles of 64

  // ---- staging constants (pre-swizzled global source) ----
  const int sr = l >> 3;                     // row within 8-row group
  const int q  = (l & 7) ^ (sr & 7);         // logical k-chunk for this lane
  const u16* sA = A  + (size_t)(m0 + w * 8 + sr) * lda + q * 8;
  const u16* sB = BT + (size_t)(n0 + w * 8 + sr) * lda + q * 8;
  const int dL = w * 512 + l * 8;            // linear LDS dest (u16)

  // ---- reader constants (swizzled ds_read addresses) ----
  const int rl  = l & 15;
  const int swz = ((kg * 4 + (l >> 4)) ^ (l & 7)) * 8;
  const int aOff = (vm * 128 + rl) * 64 + swz;          // + mi*1024
  const int bOff = 16384 + (vn * 64 + rl) * 64 + swz;   // + ni*1024

  f32x4 acc[8][4] = {};
  bf16x8 af[4], bf[4];

  auto stageH = [&](int o, int tt, int h) {
    const size_t kt = (size_t)tt * 64;
    if (h == 0) {
      stage16(sA + kt,                 lds + o + dL);
      stage16(sA + 64 * lda + kt,      lds + o + 4096 + dL);
      stage16(sB + kt,                 lds + o + 16384 + dL);
    } else {
      stage16(sA + 128 * lda + kt,     lds + o + 8192 + dL);
      stage16(sA + 192 * lda + kt,     lds + o + 12288 + dL);
      stage16(sB + 64 * lda + kt,      lds + o + 20480 + dL);
    }
  };
  auto rdA = [&](int o, int half) {
#pragma unroll
    for (int mi = 0; mi < 4; mi++)
      af[mi] = *(const bf16x8*)&lds[o + aOff + (half * 4 + mi) * 1024];
  };
  auto rdB = [&](int o) {
#pragma unroll
    for (int ni = 0; ni < 4; ni++)
      bf[ni] = *(const bf16x8*)&lds[o + bOff + ni * 1024];
  };
  auto mmq = [&](int half) {
    __builtin_amdgcn_s_setprio(1);
#pragma unroll
    for (int mi = 0; mi < 4; mi++)
#pragma unroll
      for (int ni = 0; ni < 4; ni++)
        acc[half * 4 + mi][ni] =
            __builtin_amdgcn_mfma_f32_16x16x32_bf16(af[mi], bf[ni], acc[half * 4 + mi][ni], 0, 0, 0);
    __builtin_amdgcn_s_setprio(0);
  };

  // prologue: stage tiles 0,1; tile 0 landed before interval 0
  int o0 = 0, o1 = 24576, o2 = 49152;
  stageH(o0, 0, 0); stageH(o0, 0, 1);
  if (NT > 1) {
    stageH(o1, 1, 0); stageH(o1, 1, 1);
    asm volatile("s_waitcnt vmcnt(6)" ::: "memory");
  } else {
    asm volatile("s_waitcnt vmcnt(0)" ::: "memory");
  }
  __builtin_amdgcn_s_barrier();

  for (int ti = 0; ti < NT; ++ti) {
    const bool st = (ti + 2 < NT);
    // ---- Phase A: frags(B + A-half0) | stage half0 | 16 MFMA ----
    rdB(o0);
    rdA(o0, 0);
    if (st) stageH(o2, ti + 2, 0);
    __builtin_amdgcn_s_barrier();
    asm volatile("s_waitcnt lgkmcnt(0)" ::: "memory");
    __builtin_amdgcn_sched_barrier(0);
    mmq(0);
    __builtin_amdgcn_s_barrier();
    // ---- Phase B: frags(A-half1) | stage half1 | vmcnt(6) | 16 MFMA ----
    rdA(o0, 1);
    if (st) {
      stageH(o2, ti + 2, 1);
      asm volatile("s_waitcnt vmcnt(6)" ::: "memory");
    } else {
      asm volatile("s_waitcnt vmcnt(0)" ::: "memory");
    }
    __builtin_amdgcn_s_barrier();
    asm volatile("s_waitcnt lgkmcnt(0)" ::: "memory");
    __builtin_amdgcn_sched_barrier(0);
    mmq(1);
    __builtin_amdgcn_s_barrier();
    // rotate ring
    const int tmp = o0; o0 = o1; o1 = o2; o2 = tmp;
  }

  // ---- combine the two K-subgroups' partials via LDS, then epilogue ----
  __syncthreads();
  float* pl = (float*)lds;
  if (kg == 1) {
#pragma unroll
    for (int mi = 0; mi < 8; mi++)
#pragma unroll
      for (int ni = 0; ni < 4; ni++)
        *(f32x4*)&pl[p * 8192 + (mi * 4 + ni) * 256 + l * 4] = acc[mi][ni];
  }
  __syncthreads();
  if (kg == 0) {
    const int rq = l >> 4, rl2 = l & 15;
#pragma unroll
    for (int mi = 0; mi < 8; mi++) {
#pragma unroll
      for (int ni = 0; ni < 4; ni++) {
        f32x4 p2 = *(const f32x4*)&pl[p * 8192 + (mi * 4 + ni) * 256 + l * 4];
        const int col = n0 + vn * 64 + ni * 16 + rl2;
        const float bv = bias[col];
#pragma unroll
        for (int j = 0; j < 4; j++) {
          const int row = m0 + vm * 128 + mi * 16 + rq * 4 + j;
          float vv = acc[mi][ni][j] + p2[j] + bv;
          out[(size_t)row * N + col] = f2bf(fmaxf(vv, 0.0f));
        }
      }
    }
  }
}

// -------- final GEMM (N=64) fused: sigmoid -> dist, BCE partial per block --------
__global__ __launch_bounds__(256, 2) void gemm4_fused(
    const u16* __restrict__ A, const u16* __restrict__ BT,
    const float* __restrict__ bias, const float* __restrict__ oneh,
    float* __restrict__ dist, float* __restrict__ partial)
{
  __shared__ u16 lsA[2 * 128 * 32];
  __shared__ u16 lsB[2 * 64 * 32];
  __shared__ float red[256];
  const int t = threadIdx.x, l = t & 63, w = t >> 6;
  const int m0 = blockIdx.x << 7;
  const int wm = w >> 1, wn = w & 1;

  f32x4 acc[4][2] = {};
  const int srow = l >> 2, scol = (l & 3) * 8;

  const u16* pA0 = A  + (size_t)(m0 + w * 16 + srow)      * 2048 + scol;
  const u16* pA1 = A  + (size_t)(m0 + 64 + w * 16 + srow) * 2048 + scol;
  const u16* pB0 = BT + (size_t)(w * 16 + srow)           * 2048 + scol;

  auto stage = [&](int buf, int kt) {
    u16* dA = lsA + buf * 4096;
    u16* dB = lsB + buf * 2048;
    stage16(pA0 + kt, dA + w * 512);
    stage16(pA1 + kt, dA + 2048 + w * 512);
    stage16(pB0 + kt, dB + w * 512);
  };

  stage(0, 0);
  __syncthreads();

  const int kk = (l >> 4) * 8;
  const int rl = l & 15;
  int cur = 0;
  for (int kt = 0; kt < 2048; kt += 32) {
    if (kt + 32 < 2048) stage(cur ^ 1, kt + 32);
    const u16* sA = lsA + cur * 4096;
    const u16* sB = lsB + cur * 2048;
    bf16x8 a[4], bb[2];
#pragma unroll
    for (int mi = 0; mi < 4; mi++)
      a[mi] = *(const bf16x8*)&sA[(wm * 64 + mi * 16 + rl) * 32 + kk];
#pragma unroll
    for (int ni = 0; ni < 2; ni++)
      bb[ni] = *(const bf16x8*)&sB[(wn * 32 + ni * 16 + rl) * 32 + kk];
#pragma unroll
    for (int mi = 0; mi < 4; mi++)
#pragma unroll
      for (int ni = 0; ni < 2; ni++)
        acc[mi][ni] = __builtin_amdgcn_mfma_f32_16x16x32_bf16(a[mi], bb[ni], acc[mi][ni], 0, 0, 0);
    __syncthreads();
    cur ^= 1;
  }

  float lsum = 0.0f;
  const int rq = l >> 4, rl2 = l & 15;
#pragma unroll
  for (int mi = 0; mi < 4; mi++) {
#pragma unroll
    for (int ni = 0; ni < 2; ni++) {
      const int col = wn * 32 + ni * 16 + rl2;
      const float bv = bias[col];
#pragma unroll
      for (int j = 0; j < 4; j++) {
        const int row = m0 + wm * 64 + mi * 16 + rq * 4 + j;
        const float x = acc[mi][ni][j] + bv;
        const size_t o = (size_t)row * 64 + col;
        dist[o] = 1.0f / (1.0f + expf(-x));
        const float tt = oneh[o];
        lsum += fmaxf(x, 0.0f) - x * tt + log1pf(expf(-fabsf(x)));
      }
    }
  }
  red[t] = lsum;
  __syncthreads();
  for (int s = 128; s > 0; s >>= 1) {
    if (t < s) red[t] += red[t + s];
    __syncthreads();
  }
  if (t == 0) partial[blockIdx.x] = red[0];
}

__global__ void loss_final(const float* __restrict__ partial, float* __restrict__ outloss) {
  float v = (threadIdx.x < 32) ? partial[threadIdx.x] : 0.0f;
  v = wred(v);
  if (threadIdx.x == 0) outloss[0] = v * (1.0f / 262144.0f);
}

// ---------------- launch ----------------
extern "C" void kernel_launch(void* const* d_in, const int* in_sizes, int n_in,
                              void* d_out, int out_size, void* d_ws, size_t ws_size,
                              hipStream_t stream)
{
  const float* te   = (const float*)d_in[0];
  const int*   nidx = (const int*)  d_in[1];
  const float* oneh = (const float*)d_in[2];
  const float* freq = (const float*)d_in[3];
  const float* lut  = (const float*)d_in[4];
  const float* W1   = (const float*)d_in[5];
  const float* b1   = (const float*)d_in[6];
  const float* Wh1  = (const float*)d_in[7];
  const float* bh1  = (const float*)d_in[8];
  const float* Wh2  = (const float*)d_in[9];
  const float* bh2  = (const float*)d_in[10];
  const float* W2   = (const float*)d_in[11];
  const float* b2   = (const float*)d_in[12];

  float* dist  = (float*)d_out;          // 4096*64
  float* lossp = dist + 262144;          // +1

  size_t off = 0;
  char* base = (char*)d_ws;
  auto alloc = [&](size_t bytes) { char* p = base + off; off += (bytes + 255) & ~(size_t)255; return p; };
  u16* inp   = (u16*)alloc((size_t)4096 * 8640 * 2);
  u16* w1t   = (u16*)alloc((size_t)2048 * 8640 * 2);
  u16* wh1t  = (u16*)alloc((size_t)2048 * 2048 * 2);
  u16* wh2t  = (u16*)alloc((size_t)2048 * 2048 * 2);
  u16* w2t   = (u16*)alloc((size_t)64 * 2048 * 2);
  u16* h1    = (u16*)alloc((size_t)4096 * 2048 * 2);
  float* partial = (float*)alloc(1024);
  u16* h2 = inp;    // inp dead after GEMM1
  u16* h3 = w1t;    // w1t dead after GEMM1
  if (off > ws_size) return;  // workspace too small -> clean fail

  (void)hipFuncSetAttribute((const void*)gemm8p,
                            hipFuncAttributeMaxDynamicSharedMemorySize, 147456);

  feature_kernel<<<4096, 256, 0, stream>>>(te, nidx, freq, lut, inp);
  transpose_w1 <<<135 * 32, 256, 0, stream>>>(W1, w1t);
  transpose_conv<<<32 * 32, 256, 0, stream>>>(Wh1, wh1t, 2048, 2048);
  transpose_conv<<<32 * 32, 256, 0, stream>>>(Wh2, wh2t, 2048, 2048);
  transpose_conv<<<32 * 1, 256, 0, stream>>>(W2, w2t, 2048, 64);

  gemm8p<<<256, 512, 147456, stream>>>(inp, w1t, b1, h1, 2048, 8640);
  gemm8p<<<256, 512, 147456, stream>>>(h1, wh1t, bh1, h2, 2048, 2048);
  gemm8p<<<256, 512, 147456, stream>>>(h2, wh2t, bh2, h3, 2048, 2048);
  gemm4_fused  <<<32, 256, 0, stream>>>(h3, w2t, b2, oneh, dist, partial);
  loss_final   <<<1, 64, 0, stream>>>(partial, lossp);
}

// Round 6
// 368.668 us; speedup vs baseline: 1.1111x; 1.0287x over previous
//
#include <hip/hip_runtime.h>

typedef unsigned short u16;
typedef unsigned int   u32;
typedef __attribute__((ext_vector_type(8))) __bf16 bf16x8;
typedef __attribute__((ext_vector_type(4))) float  f32x4;

#define AS1 __attribute__((address_space(1)))
#define AS3 __attribute__((address_space(3)))

// B=4096, K=64, D=128, H=2048, V=10000, IN=8640
// Permuted inp layout per row (8640 elems):
//   [0,128) u | [128,8320) v[k][d] | [8320,8576) extras k*4 | [8576,8640) popularity
// W1 rows permuted identically in transpose_w1.

__device__ __forceinline__ u16 f2bf(float f) {
  u32 u = __builtin_bit_cast(u32, f);
  u += 0x7fffu + ((u >> 16) & 1u);   // RNE (no NaN inputs here)
  return (u16)(u >> 16);
}

__device__ __forceinline__ float wred(float v) {
#pragma unroll
  for (int off = 32; off > 0; off >>= 1) v += __shfl_xor(v, off, 64);
  return v;
}

__device__ __forceinline__ void stage16(const u16* g, u16* l) {
  __builtin_amdgcn_global_load_lds((const AS1 void*)g, (AS3 void*)l, 16, 0, 0);
}

// ---------------- feature kernel ----------------
__global__ __launch_bounds__(256) void feature_kernel(
    const float* __restrict__ te, const int* __restrict__ nidx,
    const float* __restrict__ freq, const float* __restrict__ lut,
    u16* __restrict__ inp)
{
  const int b = blockIdx.x;
  const int t = threadIdx.x;
  const int l = t & 63, w = t >> 6;
  __shared__ float u_sh[128];
  __shared__ float squ_sh;

  if (t < 128) u_sh[t] = te[(size_t)b * 128 + t];
  __syncthreads();
  if (w == 0) {
    float p = u_sh[l] * u_sh[l] + u_sh[l + 64] * u_sh[l + 64];
    p = wred(p);
    if (l == 0) squ_sh = p;
  }
  const size_t rb = (size_t)b * 8640;
  if (t < 64) {
    float2 u2 = *(const float2*)&u_sh[t * 2];
    u32 pk = (u32)f2bf(u2.x) | ((u32)f2bf(u2.y) << 16);
    *(u32*)&inp[rb + t * 2] = pk;
  }
  __syncthreads();

  const float squ = squ_sh;
  const float2 u2 = *(const float2*)&u_sh[l * 2];
  for (int k = w; k < 64; k += 4) {
    const int idx = nidx[b * 64 + k];
    const float2 v2 = *(const float2*)&lut[(size_t)idx * 128 + l * 2];
    float sqv = v2.x * v2.x + v2.y * v2.y;
    float dot = u2.x * v2.x + u2.y * v2.y;
    float dx = u2.x - v2.x, dy = u2.y - v2.y;
    float sqd = dx * dx + dy * dy;
    float sx = u2.x + v2.x, sy = u2.y + v2.y;
    float ssm = sx * sx + sy * sy;
    sqv = wred(sqv); dot = wred(dot); sqd = wred(sqd); ssm = wred(ssm);

    u32 pk = (u32)f2bf(v2.x) | ((u32)f2bf(v2.y) << 16);
    *(u32*)&inp[rb + 128 + (size_t)k * 128 + l * 2] = pk;

    if (l == 0) {
      float x = 1.0f + 2.0f * sqd / ((1.0f - squ) * (1.0f - sqv));
      x = fmaxf(x, 1.0f + 1e-5f);
      float poin = logf(x + sqrtf(x * x - 1.0f));
      float cosv = dot / fmaxf(sqrtf(squ) * sqrtf(sqv), 1e-8f);
      float pol  = (ssm - sqd) * 0.25f;
      u32 p0 = (u32)f2bf(poin) | ((u32)f2bf(cosv) << 16);
      u32 p1 = (u32)f2bf(pol)  | ((u32)f2bf(dot)  << 16);
      *(u32*)&inp[rb + 8320 + k * 4]     = p0;
      *(u32*)&inp[rb + 8320 + k * 4 + 2] = p1;
      inp[rb + 8576 + k] = f2bf(log1pf(freq[idx]));
    }
  }
}

// -------- W1 transpose with feature permutation: (8640,2048) f32 -> (2048,8640) bf16 --------
__device__ __forceinline__ int w1_orig_row(int p) {
  if (p < 128) return p;
  if (p < 8320) { int q = p - 128;  return 128 + (q >> 7) * 133 + (q & 127); }
  if (p < 8576) { int q = p - 8320; return 128 + (q >> 2) * 133 + 128 + (q & 3); }
  return 128 + (p - 8576) * 133 + 132;
}

__global__ __launch_bounds__(256) void transpose_w1(
    const float* __restrict__ in, u16* __restrict__ out)
{
  __shared__ u16 ls[64][65];
  const int p0 = (blockIdx.x >> 5) << 6;   // 135 p-tiles
  const int h0 = (blockIdx.x & 31) << 6;   // 32 h-tiles
  const int t = threadIdx.x;
  const int hl = t & 63, q = t >> 6;
#pragma unroll
  for (int i = 0; i < 16; i++) {
    int pl = i * 4 + q;
    int orig = w1_orig_row(p0 + pl);
    ls[pl][hl] = f2bf(in[(size_t)orig * 2048 + h0 + hl]);
  }
  __syncthreads();
  const int pr = t & 63;
#pragma unroll
  for (int i = 0; i < 16; i++) {
    int hc = i * 4 + q;
    out[(size_t)(h0 + hc) * 8640 + p0 + pr] = ls[pr][hc];
  }
}

// -------- generic transpose+convert: in (R,C) f32 -> out (C,R) bf16 --------
__global__ __launch_bounds__(256) void transpose_conv(
    const float* __restrict__ in, u16* __restrict__ out, int R, int C)
{
  __shared__ u16 ls[64][65];
  const int tiles_c = C >> 6;
  const int r0 = (blockIdx.x / tiles_c) << 6;
  const int c0 = (blockIdx.x % tiles_c) << 6;
  const int t = threadIdx.x;
  const int cl = t & 63, q = t >> 6;
#pragma unroll
  for (int i = 0; i < 16; i++) {
    int rl = i * 4 + q;
    ls[rl][cl] = f2bf(in[(size_t)(r0 + rl) * C + c0 + cl]);
  }
  __syncthreads();
  const int rr = t & 63;
#pragma unroll
  for (int i = 0; i < 16; i++) {
    int cc = i * 4 + q;
    out[(size_t)(c0 + cc) * R + r0 + rr] = ls[rr][cc];
  }
}

// ======== gemm8p: C(M,N) = relu(A(M,Kd)*BT(N,Kd)^T + bias), out bf16 ========
// BM=256 BN=128 BK=64. 512 thr = 8 waves = 2 K-subgroups (kg=w>>2) x (2Mx2N);
// wave tile 128x64 (min LDS traffic: 96KB/interval). ONE barrier per
// interval; inside the window: stage(ti+2) -> 12 ds_reads -> lgkm(4) ->
// 16 MFMA -> lgkm(0) -> 16 MFMA -> vmcnt(6) -> barrier. No read/MFMA phase
// separation: 2 waves/SIMD skew naturally so LDS streams hide under MFMA
// (R5 lesson: barrier-separated phases serialize LDS and MFMA exactly).
// T2 slot-XOR swizzle both-sides (rule #21), counted vmcnt never 0 mid-loop
// (T4), setprio around MFMA clusters (T5 - real role diversity now).
// Ring-3 x 48KB LDS = 144KB -> 1 block/CU.
__global__ __launch_bounds__(512, 2) void gemm8p(
    const u16* __restrict__ A, const u16* __restrict__ BT,
    const float* __restrict__ bias, u16* __restrict__ out,
    int N, int Kd)
{
  extern __shared__ u16 lds[];   // 3 * 24576 u16 = 144KB
  const int t = threadIdx.x, l = t & 63, w = t >> 6;
  const int nb = N >> 7;
  const int cpx = gridDim.x >> 3;
  const int bid = (blockIdx.x & 7) * cpx + (blockIdx.x >> 3);
  const int bm = bid / nb, bn = bid % nb;
  const int m0 = bm << 8, n0 = bn << 7;

  const int kg = w >> 2;               // K32-subgroup within BK=64
  const int p  = w & 3;                // wave position
  const int vm = p >> 1, vn = p & 1;   // 2M x 2N

  const size_t lda = (size_t)Kd;
  const int NT = Kd >> 6;              // K-tiles of 64

  // ---- staging constants (pre-swizzled global source) ----
  const int sr = l >> 3;                     // row within 8-row group
  const int q  = (l & 7) ^ (sr & 7);         // logical k-chunk for this lane
  const u16* sA = A  + (size_t)(m0 + w * 8 + sr) * lda + q * 8;
  const u16* sB = BT + (size_t)(n0 + w * 8 + sr) * lda + q * 8;
  const int dL = w * 512 + l * 8;            // linear LDS dest (u16)

  // ---- reader constants (swizzled ds_read addresses) ----
  const int rl  = l & 15;
  const int swz = ((kg * 4 + (l >> 4)) ^ (l & 7)) * 8;
  const int aOff = (vm * 128 + rl) * 64 + swz;          // + mi*1024
  const int bOff = 16384 + (vn * 64 + rl) * 64 + swz;   // + ni*1024

  f32x4 acc[8][4] = {};
  bf16x8 af0[4], af1[4], bfr[4];

  auto stageT = [&](int o, int tt) {
    const size_t kt = (size_t)tt * 64;
    stage16(sA + kt,             lds + o + dL);
    stage16(sA + 64 * lda + kt,  lds + o + 4096 + dL);
    stage16(sA + 128 * lda + kt, lds + o + 8192 + dL);
    stage16(sA + 192 * lda + kt, lds + o + 12288 + dL);
    stage16(sB + kt,             lds + o + 16384 + dL);
    stage16(sB + 64 * lda + kt,  lds + o + 20480 + dL);
  };
  auto rdB = [&](int o) {
#pragma unroll
    for (int ni = 0; ni < 4; ni++)
      bfr[ni] = *(const bf16x8*)&lds[o + bOff + ni * 1024];
  };
  auto rdA0 = [&](int o) {
#pragma unroll
    for (int mi = 0; mi < 4; mi++)
      af0[mi] = *(const bf16x8*)&lds[o + aOff + mi * 1024];
  };
  auto rdA1 = [&](int o) {
#pragma unroll
    for (int mi = 0; mi < 4; mi++)
      af1[mi] = *(const bf16x8*)&lds[o + aOff + (4 + mi) * 1024];
  };
  auto mmq = [&](const bf16x8* a, int half) {
    __builtin_amdgcn_s_setprio(1);
#pragma unroll
    for (int mi = 0; mi < 4; mi++)
#pragma unroll
      for (int ni = 0; ni < 4; ni++)
        acc[half * 4 + mi][ni] =
            __builtin_amdgcn_mfma_f32_16x16x32_bf16(a[mi], bfr[ni], acc[half * 4 + mi][ni], 0, 0, 0);
    __builtin_amdgcn_s_setprio(0);
  };

  // prologue: stage tiles 0,1; tile 0 landed before interval 0
  int o0 = 0, o1 = 24576, o2 = 49152;
  stageT(o0, 0);
  if (NT > 1) {
    stageT(o1, 1);
    asm volatile("s_waitcnt vmcnt(6)" ::: "memory");
  } else {
    asm volatile("s_waitcnt vmcnt(0)" ::: "memory");
  }
  __builtin_amdgcn_s_barrier();

  for (int ti = 0; ti < NT; ++ti) {
    const bool st = (ti + 2 < NT);
    if (st) stageT(o2, ti + 2);                 // 6 vmem, non-blocking
    rdB(o0); rdA0(o0); rdA1(o0);                // 12 ds_reads outstanding
    asm volatile("s_waitcnt lgkmcnt(4)" ::: "memory");   // B + A-half0 done
    __builtin_amdgcn_sched_barrier(0);
    mmq(af0, 0);                                // A-half1 reads drain underneath
    asm volatile("s_waitcnt lgkmcnt(0)" ::: "memory");
    __builtin_amdgcn_sched_barrier(0);
    mmq(af1, 1);
    if (st) asm volatile("s_waitcnt vmcnt(6)" ::: "memory");  // ti+1 landed
    else    asm volatile("s_waitcnt vmcnt(0)" ::: "memory");
    __builtin_amdgcn_s_barrier();
    const int tmp = o0; o0 = o1; o1 = o2; o2 = tmp;
  }

  // ---- combine the two K-subgroups' partials via LDS, then epilogue ----
  __syncthreads();
  float* pl = (float*)lds;
  if (kg == 1) {
#pragma unroll
    for (int mi = 0; mi < 8; mi++)
#pragma unroll
      for (int ni = 0; ni < 4; ni++)
        *(f32x4*)&pl[p * 8192 + (mi * 4 + ni) * 256 + l * 4] = acc[mi][ni];
  }
  __syncthreads();
  if (kg == 0) {
    const int rq = l >> 4, rl2 = l & 15;
#pragma unroll
    for (int mi = 0; mi < 8; mi++) {
#pragma unroll
      for (int ni = 0; ni < 4; ni++) {
        f32x4 p2 = *(const f32x4*)&pl[p * 8192 + (mi * 4 + ni) * 256 + l * 4];
        const int col = n0 + vn * 64 + ni * 16 + rl2;
        const float bv = bias[col];
#pragma unroll
        for (int j = 0; j < 4; j++) {
          const int row = m0 + vm * 128 + mi * 16 + rq * 4 + j;
          float vv = acc[mi][ni][j] + p2[j] + bv;
          out[(size_t)row * N + col] = f2bf(fmaxf(vv, 0.0f));
        }
      }
    }
  }
}

// -------- final GEMM (N=64) fused: sigmoid -> dist, BCE partial per block --------
__global__ __launch_bounds__(256, 2) void gemm4_fused(
    const u16* __restrict__ A, const u16* __restrict__ BT,
    const float* __restrict__ bias, const float* __restrict__ oneh,
    float* __restrict__ dist, float* __restrict__ partial)
{
  __shared__ u16 lsA[2 * 128 * 32];
  __shared__ u16 lsB[2 * 64 * 32];
  __shared__ float red[256];
  const int t = threadIdx.x, l = t & 63, w = t >> 6;
  const int m0 = blockIdx.x << 7;
  const int wm = w >> 1, wn = w & 1;

  f32x4 acc[4][2] = {};
  const int srow = l >> 2, scol = (l & 3) * 8;

  const u16* pA0 = A  + (size_t)(m0 + w * 16 + srow)      * 2048 + scol;
  const u16* pA1 = A  + (size_t)(m0 + 64 + w * 16 + srow) * 2048 + scol;
  const u16* pB0 = BT + (size_t)(w * 16 + srow)           * 2048 + scol;

  auto stage = [&](int buf, int kt) {
    u16* dA = lsA + buf * 4096;
    u16* dB = lsB + buf * 2048;
    stage16(pA0 + kt, dA + w * 512);
    stage16(pA1 + kt, dA + 2048 + w * 512);
    stage16(pB0 + kt, dB + w * 512);
  };

  stage(0, 0);
  __syncthreads();

  const int kk = (l >> 4) * 8;
  const int rl = l & 15;
  int cur = 0;
  for (int kt = 0; kt < 2048; kt += 32) {
    if (kt + 32 < 2048) stage(cur ^ 1, kt + 32);
    const u16* sA = lsA + cur * 4096;
    const u16* sB = lsB + cur * 2048;
    bf16x8 a[4], bb[2];
#pragma unroll
    for (int mi = 0; mi < 4; mi++)
      a[mi] = *(const bf16x8*)&sA[(wm * 64 + mi * 16 + rl) * 32 + kk];
#pragma unroll
    for (int ni = 0; ni < 2; ni++)
      bb[ni] = *(const bf16x8*)&sB[(wn * 32 + ni * 16 + rl) * 32 + kk];
#pragma unroll
    for (int mi = 0; mi < 4; mi++)
#pragma unroll
      for (int ni = 0; ni < 2; ni++)
        acc[mi][ni] = __builtin_amdgcn_mfma_f32_16x16x32_bf16(a[mi], bb[ni], acc[mi][ni], 0, 0, 0);
    __syncthreads();
    cur ^= 1;
  }

  float lsum = 0.0f;
  const int rq = l >> 4, rl2 = l & 15;
#pragma unroll
  for (int mi = 0; mi < 4; mi++) {
#pragma unroll
    for (int ni = 0; ni < 2; ni++) {
      const int col = wn * 32 + ni * 16 + rl2;
      const float bv = bias[col];
#pragma unroll
      for (int j = 0; j < 4; j++) {
        const int row = m0 + wm * 64 + mi * 16 + rq * 4 + j;
        const float x = acc[mi][ni][j] + bv;
        const size_t o = (size_t)row * 64 + col;
        dist[o] = 1.0f / (1.0f + expf(-x));
        const float tt = oneh[o];
        lsum += fmaxf(x, 0.0f) - x * tt + log1pf(expf(-fabsf(x)));
      }
    }
  }
  red[t] = lsum;
  __syncthreads();
  for (int s = 128; s > 0; s >>= 1) {
    if (t < s) red[t] += red[t + s];
    __syncthreads();
  }
  if (t == 0) partial[blockIdx.x] = red[0];
}

__global__ void loss_final(const float* __restrict__ partial, float* __restrict__ outloss) {
  float v = (threadIdx.x < 32) ? partial[threadIdx.x] : 0.0f;
  v = wred(v);
  if (threadIdx.x == 0) outloss[0] = v * (1.0f / 262144.0f);
}

// ---------------- launch ----------------
extern "C" void kernel_launch(void* const* d_in, const int* in_sizes, int n_in,
                              void* d_out, int out_size, void* d_ws, size_t ws_size,
                              hipStream_t stream)
{
  const float* te   = (const float*)d_in[0];
  const int*   nidx = (const int*)  d_in[1];
  const float* oneh = (const float*)d_in[2];
  const float* freq = (const float*)d_in[3];
  const float* lut  = (const float*)d_in[4];
  const float* W1   = (const float*)d_in[5];
  const float* b1   = (const float*)d_in[6];
  const float* Wh1  = (const float*)d_in[7];
  const float* bh1  = (const float*)d_in[8];
  const float* Wh2  = (const float*)d_in[9];
  const float* bh2  = (const float*)d_in[10];
  const float* W2   = (const float*)d_in[11];
  const float* b2   = (const float*)d_in[12];

  float* dist  = (float*)d_out;          // 4096*64
  float* lossp = dist + 262144;          // +1

  size_t off = 0;
  char* base = (char*)d_ws;
  auto alloc = [&](size_t bytes) { char* p = base + off; off += (bytes + 255) & ~(size_t)255; return p; };
  u16* inp   = (u16*)alloc((size_t)4096 * 8640 * 2);
  u16* w1t   = (u16*)alloc((size_t)2048 * 8640 * 2);
  u16* wh1t  = (u16*)alloc((size_t)2048 * 2048 * 2);
  u16* wh2t  = (u16*)alloc((size_t)2048 * 2048 * 2);
  u16* w2t   = (u16*)alloc((size_t)64 * 2048 * 2);
  u16* h1    = (u16*)alloc((size_t)4096 * 2048 * 2);
  float* partial = (float*)alloc(1024);
  u16* h2 = inp;    // inp dead after GEMM1
  u16* h3 = w1t;    // w1t dead after GEMM1
  if (off > ws_size) return;  // workspace too small -> clean fail

  (void)hipFuncSetAttribute((const void*)gemm8p,
                            hipFuncAttributeMaxDynamicSharedMemorySize, 147456);

  feature_kernel<<<4096, 256, 0, stream>>>(te, nidx, freq, lut, inp);
  transpose_w1 <<<135 * 32, 256, 0, stream>>>(W1, w1t);
  transpose_conv<<<32 * 32, 256, 0, stream>>>(Wh1, wh1t, 2048, 2048);
  transpose_conv<<<32 * 32, 256, 0, stream>>>(Wh2, wh2t, 2048, 2048);
  transpose_conv<<<32 * 1, 256, 0, stream>>>(W2, w2t, 2048, 64);

  gemm8p<<<256, 512, 147456, stream>>>(inp, w1t, b1, h1, 2048, 8640);
  gemm8p<<<256, 512, 147456, stream>>>(h1, wh1t, bh1, h2, 2048, 2048);
  gemm8p<<<256, 512, 147456, stream>>>(h2, wh2t, bh2, h3, 2048, 2048);
  gemm4_fused  <<<32, 256, 0, stream>>>(h3, w2t, b2, oneh, dist, partial);
  loss_final   <<<1, 64, 0, stream>>>(partial, lossp);
}